// Round 10
// baseline (585.602 us; speedup 1.0000x reference)
//
#include <hip/hip_runtime.h>
#include <math.h>

#define NB 512
#define NL 336
#define NC 321
#define NS 28
#define NW 12
#define NH 25
#define NP 8
#define NG 100
#define NT (NS + NP - 1)  // 35 cell steps
#define BSL 16            // batches per wave (1 MFMA column-tile)
#define WPB 4             // independent waves per 256-thread block

typedef __attribute__((ext_vector_type(8))) short bf16x8;
typedef __attribute__((ext_vector_type(4))) float f32x4;

union B8 { bf16x8 v; short s[8]; };
union BU { bf16x8 v; unsigned u[4]; };

// round-to-nearest bf16 (weights, built once)
__device__ __forceinline__ short brtn_s(float x) {
    union { float f; unsigned u; } c; c.f = x;
    return (short)((c.u + 0x8000u) >> 16);
}
__device__ __forceinline__ float fhi_f(float x) {
    union { float f; unsigned u; } c; c.f = x; c.u &= 0xFFFF0000u; return c.f;
}
__device__ __forceinline__ short bhi_s(float x) {
    union { float f; unsigned u; } c; c.f = x; return (short)(c.u >> 16);
}
// low16 = bf16(hi of a), high16 = bf16(hi of b)
__device__ __forceinline__ unsigned pack_hi2(float a, float b) {
    union { float f; unsigned u; } x, y; x.f = a; y.f = b;
    return (x.u >> 16) | (y.u & 0xFFFF0000u);
}

// ---- software transcendentals: main-VALU-pipe only (no v_exp/v_rcp) ----
// e^{s*x}: range-reduce to e^r * 2^n, Taylor deg-5 (|r|<=0.347, rel err ~2e-6)
__device__ __forceinline__ float fexp_s(float x, float s) {
    const float y = x * s;
    const float t = y * 1.44269504088896340736f;
    const float nf = rintf(t);                       // v_rndne_f32 (VALU)
    const float r = fmaf(nf, -0.69314718055994531f, y);
    float p = 8.3333337e-3f;
    p = fmaf(p, r, 4.1666668e-2f);
    p = fmaf(p, r, 0.16666667f);
    p = fmaf(p, r, 0.5f);
    p = fmaf(p, r, 1.0f);
    p = fmaf(p, r, 1.0f);
    union { float f; int i; } pu; pu.f = p;
    pu.i += ((int)nf) << 23;                         // scale by 2^n
    return pu.f;
}
// 1/x for x >= 1 (normal): bit-trick seed + 3 Newton iters (rel err ~1e-7)
__device__ __forceinline__ float frcp_s(float x) {
    union { float f; unsigned u; } v; v.f = x;
    v.u = 0x7EF311C3u - v.u;
    float r = v.f;
    r = r * fmaf(-x, r, 2.0f);
    r = r * fmaf(-x, r, 2.0f);
    r = r * fmaf(-x, r, 2.0f);
    return r;
}

// q==3 lane carries the extra K-slots: k25=xt(hi/lo), k26=1@hi (A=bias_hi),
// k27=1@lo (A=bias_lo), k28=xt_hi@hi (A=wx_lo), k29..31=0.
__device__ __forceinline__ void set_q3(BU& h, BU& l, bool q3, float xt) {
    union { float f; unsigned u; } xu, xl;
    xu.f = xt; xl.f = xt - fhi_f(xt);
    h.u[0] = q3 ? ((h.u[0] & 0xFFFFu) | (xu.u & 0xFFFF0000u)) : h.u[0];
    l.u[0] = q3 ? ((l.u[0] & 0xFFFFu) | (xl.u & 0xFFFF0000u)) : l.u[0];
    h.u[1] = q3 ? 0x00003F80u : h.u[1];
    l.u[1] = q3 ? 0x3F800000u : l.u[1];
    h.u[2] = q3 ? (xu.u >> 16) : h.u[2];
    l.u[2] = q3 ? 0u : l.u[2];
    h.u[3] = q3 ? 0u : h.u[3];
    l.u[3] = q3 ? 0u : l.u[3];
}

// ---------------- Stage 1: mean + segment embedding (transposed out) --------
extern "C" __global__ __launch_bounds__(384)
void k_seg(const float* __restrict__ x, const float* __restrict__ seg,
           float* __restrict__ seg_inT, float* __restrict__ meanw) {
    const int b = blockIdx.x;
    const int c = threadIdx.x;
    if (c >= NC) return;
    float sw[NW];
#pragma unroll
    for (int w = 0; w < NW; ++w) sw[w] = seg[c * NW + w];
    float acc[NS];
    float sum = 0.0f;
    const float* xb = x + (size_t)b * NL * NC + c;
#pragma unroll 1
    for (int s = 0; s < NS; ++s) {
        float a = 0.0f;
#pragma unroll
        for (int w = 0; w < NW; ++w) {
            float v = xb[(s * NW + w) * NC];
            sum += v;
            a = fmaf(v, sw[w], a);
        }
        acc[s] = a;
    }
    const float mean = sum * (1.0f / (float)NL);
    float ssum = 0.0f;
#pragma unroll
    for (int w = 0; w < NW; ++w) ssum += sw[w];
    meanw[b * NC + c] = mean;
#pragma unroll
    for (int s = 0; s < NS; ++s)
        seg_inT[((size_t)s * NC + c) * NB + b] = acc[s] - mean * ssum;
}

// ---------------- Stage 2: MFMA LSTM, zero-LDS recurrence -------------------
// 4 independent waves per 256-thread block (no barriers, no LDS); each wave
// owns (channel, 16-batch tile). Gate rows permuted j=q*8+mg: lane (bb,q)
// owns h[8q..8q+7] of batch bb == exactly its next-step B-fragment slots.
// Activations: software exp/rcp (fexp_s/frcp_s) — zero trans-pipe ops.
extern "C" __global__ __launch_bounds__(256, 4)
void k_lstm(const float* __restrict__ seg_inT, const float* __restrict__ W_ih,
            const float* __restrict__ W_hh, const float* __restrict__ b_ih,
            const float* __restrict__ b_hh, const float* __restrict__ Wp,
            const float* __restrict__ bp, float* __restrict__ preds) {
    const int c = blockIdx.x;
    const int wv = threadIdx.x >> 6;
    const int lane = threadIdx.x & 63;
    const int b0 = (blockIdx.y * WPB + wv) * BSL;
    const int bb = lane & 15;         // column (batch) / A-row
    const int q  = lane >> 4;         // k-chunk / C row-quad
    const bool q3 = (q == 3);

    // ---- hoisted A-fragments from global (one-time, L2/L3-resident) ----
    const int qq = bb >> 2, rr = bb & 3;
    const float* __restrict__ whh = W_hh + (size_t)c * NG * NH;
    const float* __restrict__ wxp = W_ih + (size_t)c * NG;
    const float* __restrict__ bip = b_ih + (size_t)c * NG;
    const float* __restrict__ bhp = b_hh + (size_t)c * NG;
    bf16x8 afr[8];
#pragma unroll 1
    for (int mg = 0; mg < 8; ++mg) {
        const int jj = qq * 8 + mg;
        const int grow = rr * NH + jj;
        B8 f0;
#pragma unroll
        for (int e = 0; e < 8; ++e) {
            const int k = q * 8 + e;
            short v0 = 0;
            if (jj < NH) {
                if (k < NH)         v0 = brtn_s(whh[grow * NH + k]);
                else if (k == 25)   v0 = brtn_s(wxp[grow]);
                else if (k == 26)   v0 = bhi_s(bip[grow] + bhp[grow]);
                else if (k == 27)   { const float bs = bip[grow] + bhp[grow];
                                      v0 = brtn_s(bs - fhi_f(bs)); }
                else if (k == 28)   { const float wx = wxp[grow];
                                      v0 = brtn_s(wx - fhi_f(wx)); }
            }
            f0.s[e] = v0;
        }
        afr[mg] = f0.v;
    }

    float wpl[8];
#pragma unroll
    for (int mg = 0; mg < 8; ++mg) {
        const int j = q * 8 + mg;
        wpl[mg] = (j < NH) ? Wp[(size_t)c * NH + j] : 0.0f;
    }
    const float bpc = bp[c];

    // ---- initial B-fragments: h = 0, xt = seg_in[s=0] ----
    BU ph, pl;
    {
        const float x0 = seg_inT[(size_t)c * NB + b0 + bb];
        ph.u[0] = ph.u[1] = ph.u[2] = ph.u[3] = 0u;
        pl.u[0] = pl.u[1] = pl.u[2] = pl.u[3] = 0u;
        set_q3(ph, pl, q3, x0);
    }

    float cst[8];
#pragma unroll
    for (int mg = 0; mg < 8; ++mg) cst[mg] = 0.0f;

    // ---- recurrence: pure register dataflow ----
#pragma unroll 1
    for (int t = 0; t < NT; ++t) {
        const bool enc_next = (t + 1 < NS);
        const bool do_proj = (t >= NS - 1);
        const bool have_next = (t + 1 < NT);

        // prefetch next encoder input early (L2/L3-resident)
        float xn = 0.0f;
        if (enc_next)
            xn = seg_inT[((size_t)(t + 1) * NC + c) * NB + b0 + bb];

        float hnv[8];
        float pp = 0.0f;
#pragma unroll
        for (int mg = 0; mg < 8; ++mg) {
            f32x4 acc = {0.0f, 0.0f, 0.0f, 0.0f};
            acc = __builtin_amdgcn_mfma_f32_16x16x32_bf16(afr[mg], ph.v, acc, 0, 0, 0);
            acc = __builtin_amdgcn_mfma_f32_16x16x32_bf16(afr[mg], pl.v, acc, 0, 0, 0);
            // regs: 0=i, 1=f, 2=g, 3=o of hidden j=8q+mg, batch bb
            const float ef = fexp_s(acc[1], -1.0f);
            const float ei = fexp_s(acc[0], -1.0f);
            const float eg = fexp_s(acc[2], -2.0f);
            const float eo = fexp_s(acc[3], -1.0f);
            const float fp1 = 1.0f + ef;
            const float pig = (1.0f + ei) * (1.0f + eg);
            const float num = fmaf(cst[mg], pig, (1.0f - eg) * fp1);
            const float cn  = num * frcp_s(fp1 * pig);
            const float et  = fexp_s(cn, -2.0f);
            const float hn  = (1.0f - et) * frcp_s((1.0f + eo) * (1.0f + et));
            cst[mg] = cn;
            hnv[mg] = hn;
            if (do_proj) pp = fmaf(hn, wpl[mg], pp);
        }

        float ov = 0.0f;
        if (do_proj) {
            pp += __shfl_xor(pp, 16);
            pp += __shfl_xor(pp, 32);
            ov = pp + bpc;
            if (q == 0)
                preds[((size_t)c * NP + (t - (NS - 1))) * NB + b0 + bb] = ov;
        }

        if (have_next) {
            // repack h (hi/lo) into next step's B-fragment, in-register
#pragma unroll
            for (int e = 0; e < 4; ++e) {
                const float a = hnv[2 * e], b = hnv[2 * e + 1];
                ph.u[e] = pack_hi2(a, b);
                pl.u[e] = pack_hi2(a - fhi_f(a), b - fhi_f(b));
            }
            set_q3(ph, pl, q3, enc_next ? xn : ov);
        }
    }
}

// ---------------- Stage 3: expand predictions to output ---------------------
extern "C" __global__ __launch_bounds__(384)
void k_out(const float* __restrict__ preds, const float* __restrict__ seg,
           const float* __restrict__ meanw, float* __restrict__ out) {
    const int b = blockIdx.x;
    const int c = threadIdx.x;
    if (c >= NC) return;
    float sw[NW];
#pragma unroll
    for (int w = 0; w < NW; ++w) sw[w] = seg[c * NW + w];
    const float mean = meanw[b * NC + c];
    float pv[NP];
#pragma unroll
    for (int p = 0; p < NP; ++p) pv[p] = preds[((size_t)c * NP + p) * NB + b];
    float* ob = out + (size_t)b * (NP * NW) * NC + c;
#pragma unroll
    for (int p = 0; p < NP; ++p) {
#pragma unroll
        for (int w = 0; w < NW; ++w) {
            ob[(p * NW + w) * NC] = fmaf(pv[p], sw[w], mean);
        }
    }
}

extern "C" void kernel_launch(void* const* d_in, const int* in_sizes, int n_in,
                              void* d_out, int out_size, void* d_ws, size_t ws_size,
                              hipStream_t stream) {
    const float* x    = (const float*)d_in[0];
    const float* seg  = (const float*)d_in[1];
    const float* W_ih = (const float*)d_in[2];
    const float* W_hh = (const float*)d_in[3];
    const float* b_ih = (const float*)d_in[4];
    const float* b_hh = (const float*)d_in[5];
    const float* Wp   = (const float*)d_in[6];
    const float* bp   = (const float*)d_in[7];
    float* out = (float*)d_out;

    float* seg_inT = (float*)d_ws;                     // 28*321*512
    float* meanw   = seg_inT + (size_t)NS * NC * NB;   // 512*321
    float* preds   = meanw + (size_t)NB * NC;          // 321*8*512

    k_seg<<<NB, 384, 0, stream>>>(x, seg, seg_inT, meanw);
    k_lstm<<<dim3(NC, NB / (BSL * WPB)), 256, 0, stream>>>(
        seg_inT, W_ih, W_hh, b_ih, b_hh, Wp, bp, preds);
    k_out<<<NB, 384, 0, stream>>>(preds, seg, meanw, out);
}

// Round 11
// 473.758 us; speedup vs baseline: 1.2361x; 1.2361x over previous
//
#include <hip/hip_runtime.h>
#include <math.h>

#define NB 512
#define NL 336
#define NC 321
#define NS 28
#define NW 12
#define NH 25
#define NP 8
#define NG 100
#define NT (NS + NP - 1)  // 35 cell steps
#define BSL 16            // batches per wave (1 MFMA column-tile)
#define WPB 4             // independent waves per 256-thread block
#define LOG2E 1.44269504088896340736f
#define N2LOG2E -2.88539008177792681472f

typedef __attribute__((ext_vector_type(8))) short bf16x8;
typedef __attribute__((ext_vector_type(4))) float f32x4;

union B8 { bf16x8 v; short s[8]; };
union BU { bf16x8 v; unsigned u[4]; };

// round-to-nearest bf16 (weights, built once)
__device__ __forceinline__ short brtn_s(float x) {
    union { float f; unsigned u; } c; c.f = x;
    return (short)((c.u + 0x8000u) >> 16);
}
__device__ __forceinline__ float fhi_f(float x) {
    union { float f; unsigned u; } c; c.f = x; c.u &= 0xFFFF0000u; return c.f;
}
__device__ __forceinline__ short bhi_s(float x) {
    union { float f; unsigned u; } c; c.f = x; return (short)(c.u >> 16);
}
// low16 = bf16(hi of a), high16 = bf16(hi of b)
__device__ __forceinline__ unsigned pack_hi2(float a, float b) {
    union { float f; unsigned u; } x, y; x.f = a; y.f = b;
    return (x.u >> 16) | (y.u & 0xFFFF0000u);
}

// q==3 lane carries the extra K-slots: k25=xt(hi/lo), k26=1@hi (A=bias_hi),
// k27=1@lo (A=bias_lo), k28=xt_hi@hi (A=wx_lo), k29..31=0.
__device__ __forceinline__ void set_q3(BU& h, BU& l, bool q3, float xt) {
    union { float f; unsigned u; } xu, xl;
    xu.f = xt; xl.f = xt - fhi_f(xt);
    h.u[0] = q3 ? ((h.u[0] & 0xFFFFu) | (xu.u & 0xFFFF0000u)) : h.u[0];
    l.u[0] = q3 ? ((l.u[0] & 0xFFFFu) | (xl.u & 0xFFFF0000u)) : l.u[0];
    h.u[1] = q3 ? 0x00003F80u : h.u[1];
    l.u[1] = q3 ? 0x3F800000u : l.u[1];
    h.u[2] = q3 ? (xu.u >> 16) : h.u[2];
    l.u[2] = q3 ? 0u : l.u[2];
    h.u[3] = q3 ? 0u : h.u[3];
    l.u[3] = q3 ? 0u : l.u[3];
}

// ---------------- Stage 1: mean + segment embedding (transposed out) --------
extern "C" __global__ __launch_bounds__(384)
void k_seg(const float* __restrict__ x, const float* __restrict__ seg,
           float* __restrict__ seg_inT, float* __restrict__ meanw) {
    const int b = blockIdx.x;
    const int c = threadIdx.x;
    if (c >= NC) return;
    float sw[NW];
#pragma unroll
    for (int w = 0; w < NW; ++w) sw[w] = seg[c * NW + w];
    float acc[NS];
    float sum = 0.0f;
    const float* xb = x + (size_t)b * NL * NC + c;
#pragma unroll 1
    for (int s = 0; s < NS; ++s) {
        float a = 0.0f;
#pragma unroll
        for (int w = 0; w < NW; ++w) {
            float v = xb[(s * NW + w) * NC];
            sum += v;
            a = fmaf(v, sw[w], a);
        }
        acc[s] = a;
    }
    const float mean = sum * (1.0f / (float)NL);
    float ssum = 0.0f;
#pragma unroll
    for (int w = 0; w < NW; ++w) ssum += sw[w];
    meanw[b * NC + c] = mean;
#pragma unroll
    for (int s = 0; s < NS; ++s)
        seg_inT[((size_t)s * NC + c) * NB + b] = acc[s] - mean * ssum;
}

// ---------------- Stage 2: MFMA LSTM, zero-LDS recurrence -------------------
// 4 independent waves per 256-thread block (no barriers, no LDS); each wave
// owns (channel, 16-batch tile). Gate rows permuted j=q*8+mg: lane (bb,q)
// owns h[8q..8q+7] of batch bb == exactly its next-step B-fragment slots.
// Gates emerge from MFMA pre-scaled into exp2 domain (log2e folded into
// W/wx/bias rows; 2*log2e for gate g) -> activations are single-instruction
// v_exp_f32 / v_rcp_f32, phase-structured for cross-unit ILP.
extern "C" __global__ __launch_bounds__(256, 4)
void k_lstm(const float* __restrict__ seg_inT, const float* __restrict__ W_ih,
            const float* __restrict__ W_hh, const float* __restrict__ b_ih,
            const float* __restrict__ b_hh, const float* __restrict__ Wp,
            const float* __restrict__ bp, float* __restrict__ preds) {
    const int c = blockIdx.x;
    const int wv = threadIdx.x >> 6;
    const int lane = threadIdx.x & 63;
    const int b0 = (blockIdx.y * WPB + wv) * BSL;
    const int bb = lane & 15;         // column (batch) / A-row
    const int q  = lane >> 4;         // k-chunk / C row-quad
    const bool q3 = (q == 3);

    // ---- hoisted A-fragments from global (one-time, L2/L3-resident) ----
    // A-row bb of MFMA #mg = gate-row grow=(bb&3)*NH + (bb>>2)*8+mg, k=q*8+e
    const int qq = bb >> 2, rr = bb & 3;
    const float srow = (rr == 2) ? 2.88539008177792681472f : LOG2E;
    const float* __restrict__ whh = W_hh + (size_t)c * NG * NH;
    const float* __restrict__ wxp = W_ih + (size_t)c * NG;
    const float* __restrict__ bip = b_ih + (size_t)c * NG;
    const float* __restrict__ bhp = b_hh + (size_t)c * NG;
    bf16x8 afr[8];
#pragma unroll 1
    for (int mg = 0; mg < 8; ++mg) {
        const int jj = qq * 8 + mg;
        const int grow = rr * NH + jj;
        B8 f0;
#pragma unroll
        for (int e = 0; e < 8; ++e) {
            const int k = q * 8 + e;
            short v0 = 0;
            if (jj < NH) {
                if (k < NH)         v0 = brtn_s(whh[grow * NH + k] * srow);
                else if (k == 25)   v0 = brtn_s(wxp[grow] * srow);
                else if (k == 26)   v0 = bhi_s((bip[grow] + bhp[grow]) * srow);
                else if (k == 27)   { const float bs = (bip[grow] + bhp[grow]) * srow;
                                      v0 = brtn_s(bs - fhi_f(bs)); }
                else if (k == 28)   { const float wx = wxp[grow] * srow;
                                      v0 = brtn_s(wx - fhi_f(wx)); }
            }
            f0.s[e] = v0;
        }
        afr[mg] = f0.v;
    }

    float wpl[8];
#pragma unroll
    for (int mg = 0; mg < 8; ++mg) {
        const int j = q * 8 + mg;
        wpl[mg] = (j < NH) ? Wp[(size_t)c * NH + j] : 0.0f;
    }
    const float bpc = bp[c];

    // ---- initial B-fragments: h = 0, xt = seg_in[s=0] ----
    BU ph, pl;
    {
        const float x0 = seg_inT[(size_t)c * NB + b0 + bb];
        ph.u[0] = ph.u[1] = ph.u[2] = ph.u[3] = 0u;
        pl.u[0] = pl.u[1] = pl.u[2] = pl.u[3] = 0u;
        set_q3(ph, pl, q3, x0);
    }

    float cst[8];
#pragma unroll
    for (int mg = 0; mg < 8; ++mg) cst[mg] = 0.0f;

    // ---- recurrence: pure register dataflow, phase-structured ----
#pragma unroll 1
    for (int t = 0; t < NT; ++t) {
        const bool enc_next = (t + 1 < NS);
        const bool do_proj = (t >= NS - 1);
        const bool have_next = (t + 1 < NT);

        // prefetch next encoder input early (L2/L3-resident)
        float xn = 0.0f;
        if (enc_next)
            xn = seg_inT[((size_t)(t + 1) * NC + c) * NB + b0 + bb];

        // phase 1: all 16 MFMAs (independent)
        f32x4 av[8];
#pragma unroll
        for (int mg = 0; mg < 8; ++mg) {
            f32x4 a = {0.0f, 0.0f, 0.0f, 0.0f};
            a = __builtin_amdgcn_mfma_f32_16x16x32_bf16(afr[mg], ph.v, a, 0, 0, 0);
            av[mg] = __builtin_amdgcn_mfma_f32_16x16x32_bf16(afr[mg], pl.v, a, 0, 0, 0);
        }

        // phase 2: all 32 gate exps (single v_exp_f32 each; exp2 domain)
        float ei[8], ef[8], eg[8], eo[8];
#pragma unroll
        for (int mg = 0; mg < 8; ++mg) {
            ei[mg] = __builtin_amdgcn_exp2f(-av[mg][0]);
            ef[mg] = __builtin_amdgcn_exp2f(-av[mg][1]);
            eg[mg] = __builtin_amdgcn_exp2f(-av[mg][2]);
            eo[mg] = __builtin_amdgcn_exp2f(-av[mg][3]);
        }

        // phase 3: per-unit tails (independent across mg)
        float hnv[8];
        float pp = 0.0f;
#pragma unroll
        for (int mg = 0; mg < 8; ++mg) {
            const float p1f = 1.0f + ef[mg];
            const float pig = (1.0f + ei[mg]) * (1.0f + eg[mg]);
            const float num = fmaf(cst[mg], pig, (1.0f - eg[mg]) * p1f);
            const float cn  = num * __builtin_amdgcn_rcpf(p1f * pig);
            const float et  = __builtin_amdgcn_exp2f(cn * N2LOG2E);
            const float hn  = (1.0f - et) *
                              __builtin_amdgcn_rcpf((1.0f + eo[mg]) * (1.0f + et));
            cst[mg] = cn;
            hnv[mg] = hn;
            if (do_proj) pp = fmaf(hn, wpl[mg], pp);
        }

        float ov = 0.0f;
        if (do_proj) {
            pp += __shfl_xor(pp, 16);
            pp += __shfl_xor(pp, 32);
            ov = pp + bpc;
            if (q == 0)
                preds[((size_t)c * NP + (t - (NS - 1))) * NB + b0 + bb] = ov;
        }

        if (have_next) {
            // repack h (hi/lo) into next step's B-fragment, in-register
#pragma unroll
            for (int e = 0; e < 4; ++e) {
                const float a = hnv[2 * e], b = hnv[2 * e + 1];
                ph.u[e] = pack_hi2(a, b);
                pl.u[e] = pack_hi2(a - fhi_f(a), b - fhi_f(b));
            }
            set_q3(ph, pl, q3, enc_next ? xn : ov);
        }
    }
}

// ---------------- Stage 3: expand predictions to output ---------------------
extern "C" __global__ __launch_bounds__(384)
void k_out(const float* __restrict__ preds, const float* __restrict__ seg,
           const float* __restrict__ meanw, float* __restrict__ out) {
    const int b = blockIdx.x;
    const int c = threadIdx.x;
    if (c >= NC) return;
    float sw[NW];
#pragma unroll
    for (int w = 0; w < NW; ++w) sw[w] = seg[c * NW + w];
    const float mean = meanw[b * NC + c];
    float pv[NP];
#pragma unroll
    for (int p = 0; p < NP; ++p) pv[p] = preds[((size_t)c * NP + p) * NB + b];
    float* ob = out + (size_t)b * (NP * NW) * NC + c;
#pragma unroll
    for (int p = 0; p < NP; ++p) {
#pragma unroll
        for (int w = 0; w < NW; ++w) {
            ob[(p * NW + w) * NC] = fmaf(pv[p], sw[w], mean);
        }
    }
}

extern "C" void kernel_launch(void* const* d_in, const int* in_sizes, int n_in,
                              void* d_out, int out_size, void* d_ws, size_t ws_size,
                              hipStream_t stream) {
    const float* x    = (const float*)d_in[0];
    const float* seg  = (const float*)d_in[1];
    const float* W_ih = (const float*)d_in[2];
    const float* W_hh = (const float*)d_in[3];
    const float* b_ih = (const float*)d_in[4];
    const float* b_hh = (const float*)d_in[5];
    const float* Wp   = (const float*)d_in[6];
    const float* bp   = (const float*)d_in[7];
    float* out = (float*)d_out;

    float* seg_inT = (float*)d_ws;                     // 28*321*512
    float* meanw   = seg_inT + (size_t)NS * NC * NB;   // 512*321
    float* preds   = meanw + (size_t)NB * NC;          // 321*8*512

    k_seg<<<NB, 384, 0, stream>>>(x, seg, seg_inT, meanw);
    k_lstm<<<dim3(NC, NB / (BSL * WPB)), 256, 0, stream>>>(
        seg_inT, W_ih, W_hh, b_ih, b_hh, Wp, bp, preds);
    k_out<<<NB, 384, 0, stream>>>(preds, seg, meanw, out);
}

// Round 12
// 332.643 us; speedup vs baseline: 1.7604x; 1.4242x over previous
//
#include <hip/hip_runtime.h>
#include <math.h>

#define NB 512
#define NL 336
#define NC 321
#define NS 28
#define NW 12
#define NH 25
#define NP 8
#define NG 100
#define NT (NS + NP - 1)  // 35 cell steps
#define BSL 16            // batches per wave (1 MFMA column-tile)
#define WPB 4             // independent waves per 256-thread block
#define LOG2E 1.44269504088896340736f
#define N2LOG2E -2.88539008177792681472f

typedef __attribute__((ext_vector_type(8))) _Float16 f16x8;
typedef __attribute__((ext_vector_type(4))) float f32x4;

union F8 { f16x8 v; _Float16 h[8]; };

// q==3 lane carries the extra K-slots: k25=xt, k26=1.0 (A=bias row), k27..31=0
__device__ __forceinline__ void set_q3f(F8& b, bool q3, float xt) {
    b.h[1] = q3 ? (_Float16)xt : b.h[1];
    b.h[2] = q3 ? (_Float16)1.0f : b.h[2];
    b.h[3] = q3 ? (_Float16)0.0f : b.h[3];
    b.h[4] = q3 ? (_Float16)0.0f : b.h[4];
    b.h[5] = q3 ? (_Float16)0.0f : b.h[5];
    b.h[6] = q3 ? (_Float16)0.0f : b.h[6];
    b.h[7] = q3 ? (_Float16)0.0f : b.h[7];
}

// ---------------- Stage 1: mean + segment embedding (transposed out) --------
extern "C" __global__ __launch_bounds__(384)
void k_seg(const float* __restrict__ x, const float* __restrict__ seg,
           float* __restrict__ seg_inT, float* __restrict__ meanw) {
    const int b = blockIdx.x;
    const int c = threadIdx.x;
    if (c >= NC) return;
    float sw[NW];
#pragma unroll
    for (int w = 0; w < NW; ++w) sw[w] = seg[c * NW + w];
    float acc[NS];
    float sum = 0.0f;
    const float* xb = x + (size_t)b * NL * NC + c;
#pragma unroll 1
    for (int s = 0; s < NS; ++s) {
        float a = 0.0f;
#pragma unroll
        for (int w = 0; w < NW; ++w) {
            float v = xb[(s * NW + w) * NC];
            sum += v;
            a = fmaf(v, sw[w], a);
        }
        acc[s] = a;
    }
    const float mean = sum * (1.0f / (float)NL);
    float ssum = 0.0f;
#pragma unroll
    for (int w = 0; w < NW; ++w) ssum += sw[w];
    meanw[b * NC + c] = mean;
#pragma unroll
    for (int s = 0; s < NS; ++s)
        seg_inT[((size_t)s * NC + c) * NB + b] = acc[s] - mean * ssum;
}

// ---------------- Stage 2: f16-MFMA LSTM, zero-LDS recurrence ---------------
// 4 independent waves per 256-thread block (no barriers, no LDS); each wave
// owns (channel, 16-batch tile). Gate rows permuted j=q*8+mg: lane (bb,q)
// owns h[8q..8q+7] of batch bb == exactly its next-step B-fragment slots.
// f16 weights/h (11-bit mantissa: weights MORE precise than prior bf16-RTN,
// h error stays under weight noise) -> single MFMA per gate-tile, trivial
// repack. Gates emerge pre-scaled into exp2 domain (log2e folded into rows;
// 2*log2e for gate g) -> activations are single v_exp_f32 / v_rcp_f32.
extern "C" __global__ __launch_bounds__(256, 4)
void k_lstm(const float* __restrict__ seg_inT, const float* __restrict__ W_ih,
            const float* __restrict__ W_hh, const float* __restrict__ b_ih,
            const float* __restrict__ b_hh, const float* __restrict__ Wp,
            const float* __restrict__ bp, float* __restrict__ preds) {
    const int c = blockIdx.x;
    const int wv = threadIdx.x >> 6;
    const int lane = threadIdx.x & 63;
    const int b0 = (blockIdx.y * WPB + wv) * BSL;
    const int bb = lane & 15;         // column (batch) / A-row
    const int q  = lane >> 4;         // k-chunk / C row-quad
    const bool q3 = (q == 3);

    // ---- hoisted A-fragments from global (one-time, L2/L3-resident) ----
    // A-row bb of MFMA #mg = gate-row grow=(bb&3)*NH + (bb>>2)*8+mg, k=q*8+e
    const int qq = bb >> 2, rr = bb & 3;
    const float srow = (rr == 2) ? 2.88539008177792681472f : LOG2E;
    const float* __restrict__ whh = W_hh + (size_t)c * NG * NH;
    const float* __restrict__ wxp = W_ih + (size_t)c * NG;
    const float* __restrict__ bip = b_ih + (size_t)c * NG;
    const float* __restrict__ bhp = b_hh + (size_t)c * NG;
    F8 afr[8];
#pragma unroll 1
    for (int mg = 0; mg < 8; ++mg) {
        const int jj = qq * 8 + mg;
        const int grow = rr * NH + jj;
        F8 f0;
#pragma unroll
        for (int e = 0; e < 8; ++e) {
            const int k = q * 8 + e;
            float v0 = 0.0f;
            if (jj < NH) {
                if (k < NH)         v0 = whh[grow * NH + k] * srow;
                else if (k == 25)   v0 = wxp[grow] * srow;
                else if (k == 26)   v0 = (bip[grow] + bhp[grow]) * srow;
            }
            f0.h[e] = (_Float16)v0;
        }
        afr[mg] = f0;
    }

    float wpl[8];
#pragma unroll
    for (int mg = 0; mg < 8; ++mg) {
        const int j = q * 8 + mg;
        wpl[mg] = (j < NH) ? Wp[(size_t)c * NH + j] : 0.0f;
    }
    const float bpc = bp[c];

    // ---- initial B-fragment: h = 0, xt = seg_in[s=0] ----
    F8 ph;
    {
        const float x0 = seg_inT[(size_t)c * NB + b0 + bb];
#pragma unroll
        for (int e = 0; e < 8; ++e) ph.h[e] = (_Float16)0.0f;
        set_q3f(ph, q3, x0);
    }

    float cst[8];
#pragma unroll
    for (int mg = 0; mg < 8; ++mg) cst[mg] = 0.0f;

    // ---- recurrence: pure register dataflow, phase-structured ----
#pragma unroll 1
    for (int t = 0; t < NT; ++t) {
        const bool enc_next = (t + 1 < NS);
        const bool do_proj = (t >= NS - 1);
        const bool have_next = (t + 1 < NT);

        // prefetch next encoder input early (L2/L3-resident)
        float xn = 0.0f;
        if (enc_next)
            xn = seg_inT[((size_t)(t + 1) * NC + c) * NB + b0 + bb];

        // phase 1: all 8 MFMAs (independent, single per gate-tile)
        f32x4 av[8];
#pragma unroll
        for (int mg = 0; mg < 8; ++mg) {
            f32x4 z = {0.0f, 0.0f, 0.0f, 0.0f};
            av[mg] = __builtin_amdgcn_mfma_f32_16x16x32_f16(afr[mg].v, ph.v, z, 0, 0, 0);
        }

        // phase 2: all 32 gate exps (single v_exp_f32 each; exp2 domain)
        float ei[8], ef[8], eg[8], eo[8];
#pragma unroll
        for (int mg = 0; mg < 8; ++mg) {
            ei[mg] = __builtin_amdgcn_exp2f(-av[mg][0]);
            ef[mg] = __builtin_amdgcn_exp2f(-av[mg][1]);
            eg[mg] = __builtin_amdgcn_exp2f(-av[mg][2]);
            eo[mg] = __builtin_amdgcn_exp2f(-av[mg][3]);
        }

        // phase 3: per-unit tails (independent across mg)
        float hnv[8];
        float pp = 0.0f;
#pragma unroll
        for (int mg = 0; mg < 8; ++mg) {
            const float p1f = 1.0f + ef[mg];
            const float pig = (1.0f + ei[mg]) * (1.0f + eg[mg]);
            const float num = fmaf(cst[mg], pig, (1.0f - eg[mg]) * p1f);
            const float cn  = num * __builtin_amdgcn_rcpf(p1f * pig);
            const float et  = __builtin_amdgcn_exp2f(cn * N2LOG2E);
            const float hn  = (1.0f - et) *
                              __builtin_amdgcn_rcpf((1.0f + eo[mg]) * (1.0f + et));
            cst[mg] = cn;
            hnv[mg] = hn;
            if (do_proj) pp = fmaf(hn, wpl[mg], pp);
        }

        float ov = 0.0f;
        if (do_proj) {
            pp += __shfl_xor(pp, 16);
            pp += __shfl_xor(pp, 32);
            ov = pp + bpc;
            if (q == 0)
                preds[((size_t)c * NP + (t - (NS - 1))) * NB + b0 + bb] = ov;
        }

        if (have_next) {
            // repack h into next step's B-fragment: 8 f32->f16 converts
#pragma unroll
            for (int e = 0; e < 8; ++e) ph.h[e] = (_Float16)hnv[e];
            set_q3f(ph, q3, enc_next ? xn : ov);
        }
    }
}

// ---------------- Stage 3: expand predictions to output ---------------------
extern "C" __global__ __launch_bounds__(384)
void k_out(const float* __restrict__ preds, const float* __restrict__ seg,
           const float* __restrict__ meanw, float* __restrict__ out) {
    const int b = blockIdx.x;
    const int c = threadIdx.x;
    if (c >= NC) return;
    float sw[NW];
#pragma unroll
    for (int w = 0; w < NW; ++w) sw[w] = seg[c * NW + w];
    const float mean = meanw[b * NC + c];
    float pv[NP];
#pragma unroll
    for (int p = 0; p < NP; ++p) pv[p] = preds[((size_t)c * NP + p) * NB + b];
    float* ob = out + (size_t)b * (NP * NW) * NC + c;
#pragma unroll
    for (int p = 0; p < NP; ++p) {
#pragma unroll
        for (int w = 0; w < NW; ++w) {
            ob[(p * NW + w) * NC] = fmaf(pv[p], sw[w], mean);
        }
    }
}

extern "C" void kernel_launch(void* const* d_in, const int* in_sizes, int n_in,
                              void* d_out, int out_size, void* d_ws, size_t ws_size,
                              hipStream_t stream) {
    const float* x    = (const float*)d_in[0];
    const float* seg  = (const float*)d_in[1];
    const float* W_ih = (const float*)d_in[2];
    const float* W_hh = (const float*)d_in[3];
    const float* b_ih = (const float*)d_in[4];
    const float* b_hh = (const float*)d_in[5];
    const float* Wp   = (const float*)d_in[6];
    const float* bp   = (const float*)d_in[7];
    float* out = (float*)d_out;

    float* seg_inT = (float*)d_ws;                     // 28*321*512
    float* meanw   = seg_inT + (size_t)NS * NC * NB;   // 512*321
    float* preds   = meanw + (size_t)NB * NC;          // 321*8*512

    k_seg<<<NB, 384, 0, stream>>>(x, seg, seg_inT, meanw);
    k_lstm<<<dim3(NC, NB / (BSL * WPB)), 256, 0, stream>>>(
        seg_inT, W_ih, W_hh, b_ih, b_hh, Wp, bp, preds);
    k_out<<<NB, 384, 0, stream>>>(preds, seg, meanw, out);
}